// Round 16
// baseline (323.794 us; speedup 1.0000x reference)
//
#include <hip/hip_runtime.h>

#define SCALE 0.125f

constexpr int L_ = 1024, T_ = 1024, D_ = 64, HB_ = 64;

using f32x4 = __attribute__((ext_vector_type(4))) float;
using half8 = __attribute__((ext_vector_type(8))) _Float16;
using half4 = __attribute__((ext_vector_type(4))) _Float16;

// ===========================================================================
// Prologue: V f32 [hb][t][d] -> Vh f16 transposed [hb][d][t]. (r10-proven)
// ===========================================================================
__global__ __launch_bounds__(256) void cvt_v(const float* __restrict__ v,
                                             _Float16* __restrict__ vh) {
  __shared__ _Float16 ts[64][136];
  const int tid = threadIdx.x;
  const int hb = blockIdx.y;
  const int t0 = blockIdx.x * 128;
  {
    const int tr = tid >> 1, dh = (tid & 1) * 32;
    const float* p = v + ((size_t)hb * T_ + t0 + tr) * D_ + dh;
#pragma unroll
    for (int i = 0; i < 8; ++i) {
      f32x4 r = *(const f32x4*)(p + i * 4);
#pragma unroll
      for (int e = 0; e < 4; ++e) ts[dh + i * 4 + e][tr] = (_Float16)r[e];
    }
  }
  __syncthreads();
  {
    const int d = tid >> 2, tq = (tid & 3) * 32;
    _Float16* qo = vh + ((size_t)hb * D_ + d) * T_ + t0 + tq;
#pragma unroll
    for (int i = 0; i < 4; ++i)
      *(half8*)(qo + i * 8) = *(const half8*)&ts[d][tq + i * 8];
  }
}

// ===========================================================================
// Fused kernel: 1024 threads (16 waves), 256 q-rows/block, grid 4x64 = 256
// blocks = exactly 1 per CU (4 waves/SIMD). Full per-hb K staged to LDS once
// (f32->f16, 143 KB). Wave w owns rows w*16..+15, independent after staging:
//  Phase 1: QK^T (LDS) + prev (HBM, depth-2 reg prefetch) -> Z only.
//  Phase 2: re-read prev (L3-hot), recompute QK^T+exp, normalize f32,
//           stream att (dense 64B sectors), PV via zero-padded reg A-frags
//           (r8-validated: swapped-QK output IS the PV A-fragment) and
//           half4 V^T global loads issued before the prev prefetch so the
//           vmcnt queue never back-drains (r13 lesson). No El LDS at all.
// ===========================================================================
__global__ __launch_bounds__(1024) void attn_all(
    const float* __restrict__ q, const float* __restrict__ kk,
    const _Float16* __restrict__ Vh, const float* __restrict__ prev,
    float* __restrict__ out, float* __restrict__ att) {
  __shared__ __align__(16) _Float16 Ks[1024][70];   // 143,360 B full-T K

  const int ltile = blockIdx.x;   // 0..3
  const int hb    = blockIdx.y;   // 0..63
  const int tid = threadIdx.x;
  const int w = tid >> 6, l = tid & 63, l15 = l & 15, lg = l >> 4;
  const int qrow = ltile * 256 + w * 16 + l15;

  // ---- stage ALL of K (f32 -> f16): 4 reps x (1024 thr x 16 floats)
  {
    const int srow = tid >> 2, scol = (tid & 3) * 16;
    const float* kp0 = kk + (size_t)hb * T_ * D_;
#pragma unroll
    for (int rep = 0; rep < 4; ++rep) {
      const int r = rep * 256 + srow;
      const float* p = kp0 + (size_t)r * D_ + scol;
      f32x4 a = *(const f32x4*)(p);
      f32x4 b = *(const f32x4*)(p + 4);
      f32x4 cc = *(const f32x4*)(p + 8);
      f32x4 d = *(const f32x4*)(p + 12);
      half8 h0, h1;
#pragma unroll
      for (int e = 0; e < 4; ++e) {
        h0[e] = (_Float16)a[e];  h0[4 + e] = (_Float16)b[e];
        h1[e] = (_Float16)cc[e]; h1[4 + e] = (_Float16)d[e];
      }
      *(half8*)&Ks[r][scol] = h0;
      *(half8*)&Ks[r][scol + 8] = h1;
    }
  }

  // Q B-frag (swapped QK^T): lane holds Q[qrow][f*32 + lg*8 + e]
  half8 qb2[2];
  {
    const float* qp = q + ((size_t)hb * L_ + qrow) * D_ + lg * 8;
#pragma unroll
    for (int f = 0; f < 2; ++f)
#pragma unroll
      for (int e = 0; e < 8; ++e) qb2[f][e] = (_Float16)qp[f * 32 + e];
  }

  const float* prow = prev + ((size_t)hb * L_ + qrow) * (size_t)T_;

  f32x4 pb[2][4];
  auto pload = [&](int c, int s) {
#pragma unroll
    for (int nt = 0; nt < 4; ++nt)
      pb[s][nt] = *(const f32x4*)(prow + c * 64 + nt * 16 + lg * 4);
  };

  __syncthreads();   // K staged; no further block barriers

  // ======================= Phase 1: Z only ================================
  pload(0, 0);
  pload(1, 1);
  float zsum = 0.f;

#pragma unroll 2
  for (int c = 0; c < 16; ++c) {
    f32x4 pvv[4];
#pragma unroll
    for (int nt = 0; nt < 4; ++nt) pvv[nt] = pb[c & 1][nt];
    if (c < 14) pload(c + 2, c & 1);

#pragma unroll
    for (int nt = 0; nt < 4; ++nt) {
      const int trow = c * 64 + nt * 16 + l15;
      half8 ka0 = *(const half8*)&Ks[trow][lg * 8];
      half8 ka1 = *(const half8*)&Ks[trow][32 + lg * 8];
      f32x4 acc = {0.f, 0.f, 0.f, 0.f};
      acc = __builtin_amdgcn_mfma_f32_16x16x32_f16(ka0, qb2[0], acc, 0, 0, 0);
      acc = __builtin_amdgcn_mfma_f32_16x16x32_f16(ka1, qb2[1], acc, 0, 0, 0);
      zsum += __expf(acc[0] * SCALE + pvv[nt][0]);
      zsum += __expf(acc[1] * SCALE + pvv[nt][1]);
      zsum += __expf(acc[2] * SCALE + pvv[nt][2]);
      zsum += __expf(acc[3] * SCALE + pvv[nt][3]);
    }
  }

  // Z for row l15: reduce the 4 lg lanes; result lands in ALL lanes
  zsum += __shfl_xor(zsum, 16, 64);
  zsum += __shfl_xor(zsum, 32, 64);
  const float rzq = 1.0f / zsum;

  // ======================= Phase 2: att + PV ==============================
  const _Float16* vbh = Vh + (size_t)hb * D_ * T_;  // [d][t] f16
  float* arow = att + ((size_t)hb * L_ + qrow) * (size_t)T_;

  pload(0, 0);   // re-read (L3-hot)
  pload(1, 1);

  f32x4 oacc[4];
#pragma unroll
  for (int nd = 0; nd < 4; ++nd) oacc[nd] = (f32x4){0.f, 0.f, 0.f, 0.f};

#pragma unroll 2
  for (int c = 0; c < 16; ++c) {
    // ALL V fragment loads first (older than the prev prefetch below, so
    // consuming them never drains it; they're L2-hot half4 reads)
    half4 vr[4][4];
#pragma unroll
    for (int nt = 0; nt < 4; ++nt)
#pragma unroll
      for (int nd = 0; nd < 4; ++nd)
        vr[nt][nd] = *(const half4*)(vbh + (size_t)(nd * 16 + l15) * T_ +
                                     c * 64 + nt * 16 + lg * 4);

    f32x4 pvv[4];
#pragma unroll
    for (int nt = 0; nt < 4; ++nt) pvv[nt] = pb[c & 1][nt];
    if (c < 14) pload(c + 2, c & 1);

#pragma unroll
    for (int nt = 0; nt < 4; ++nt) {
      const int trow = c * 64 + nt * 16 + l15;
      half8 ka0 = *(const half8*)&Ks[trow][lg * 8];
      half8 ka1 = *(const half8*)&Ks[trow][32 + lg * 8];
      f32x4 acc = {0.f, 0.f, 0.f, 0.f};
      acc = __builtin_amdgcn_mfma_f32_16x16x32_f16(ka0, qb2[0], acc, 0, 0, 0);
      acc = __builtin_amdgcn_mfma_f32_16x16x32_f16(ka1, qb2[1], acc, 0, 0, 0);

      f32x4 s;
      s[0] = __expf(acc[0] * SCALE + pvv[nt][0]) * rzq;
      s[1] = __expf(acc[1] * SCALE + pvv[nt][1]) * rzq;
      s[2] = __expf(acc[2] * SCALE + pvv[nt][2]) * rzq;
      s[3] = __expf(acc[3] * SCALE + pvv[nt][3]) * rzq;
      *(f32x4*)(arow + c * 64 + nt * 16 + lg * 4) = s;

      // reg-PV (r8-validated): af k-slot lg*8+i <-> t = nt*16 + lg*4 + i
      half8 af;
      af[0] = (_Float16)s[0]; af[1] = (_Float16)s[1];
      af[2] = (_Float16)s[2]; af[3] = (_Float16)s[3];
      af[4] = af[5] = af[6] = af[7] = (_Float16)0.f;
#pragma unroll
      for (int nd = 0; nd < 4; ++nd) {
        half8 vb;
        vb[0] = vr[nt][nd][0]; vb[1] = vr[nt][nd][1];
        vb[2] = vr[nt][nd][2]; vb[3] = vr[nt][nd][3];
        vb[4] = vb[5] = vb[6] = vb[7] = (_Float16)0.f;
        oacc[nd] =
            __builtin_amdgcn_mfma_f32_16x16x32_f16(af, vb, oacc[nd], 0, 0, 0);
      }
    }
  }

  // epilogue: oacc[nd][i] = O[q = w*16 + lg*4 + i][d = nd*16 + l15]
  // (already normalized since A was normalized)
  float* outw =
      out + ((size_t)hb * L_ + ltile * 256 + w * 16 + lg * 4) * (size_t)D_;
#pragma unroll
  for (int nd = 0; nd < 4; ++nd)
#pragma unroll
    for (int i = 0; i < 4; ++i)
      outw[(size_t)i * D_ + nd * 16 + l15] = oacc[nd][i];
}

extern "C" void kernel_launch(void* const* d_in, const int* in_sizes, int n_in,
                              void* d_out, int out_size, void* d_ws,
                              size_t ws_size, hipStream_t stream) {
  const float* q    = (const float*)d_in[0];  // (H,B,L,D)
  const float* k    = (const float*)d_in[1];  // (H,B,T,D)
  const float* v    = (const float*)d_in[2];  // (H,B,T,D)
  const float* prev = (const float*)d_in[3];  // (H,B,L,T)

  float* out = (float*)d_out;                 // (H,B,L,D)
  float* att = out + (size_t)HB_ * L_ * D_;   // (H,B,L,T)

  _Float16* Vh = (_Float16*)d_ws;             // 8 MB (ws >= 16 MB proven)

  cvt_v<<<dim3(T_ / 128, HB_), 256, 0, stream>>>(v, Vh);
  attn_all<<<dim3(L_ / 256, HB_), 1024, 0, stream>>>(q, k, Vh, prev, out, att);
}

// Round 17
// 226.944 us; speedup vs baseline: 1.4268x; 1.4268x over previous
//
#include <hip/hip_runtime.h>

#define SCALE 0.125f

constexpr int L_ = 1024, T_ = 1024, D_ = 64, HB_ = 64;

using f32x4 = __attribute__((ext_vector_type(4))) float;
using half8 = __attribute__((ext_vector_type(8))) _Float16;
using half4 = __attribute__((ext_vector_type(4))) _Float16;

// ===========================================================================
// Prologue: V f32 [hb][t][d] -> Vh f16 transposed [hb][d][t]. (r10-proven)
// ===========================================================================
__global__ __launch_bounds__(256) void cvt_v(const float* __restrict__ v,
                                             _Float16* __restrict__ vh) {
  __shared__ _Float16 ts[64][136];
  const int tid = threadIdx.x;
  const int hb = blockIdx.y;
  const int t0 = blockIdx.x * 128;
  {
    const int tr = tid >> 1, dh = (tid & 1) * 32;
    const float* p = v + ((size_t)hb * T_ + t0 + tr) * D_ + dh;
#pragma unroll
    for (int i = 0; i < 8; ++i) {
      f32x4 r = *(const f32x4*)(p + i * 4);
#pragma unroll
      for (int e = 0; e < 4; ++e) ts[dh + i * 4 + e][tr] = (_Float16)r[e];
    }
  }
  __syncthreads();
  {
    const int d = tid >> 2, tq = (tid & 3) * 32;
    _Float16* qo = vh + ((size_t)hb * D_ + d) * T_ + t0 + tq;
#pragma unroll
    for (int i = 0; i < 4; ++i)
      *(half8*)(qo + i * 8) = *(const half8*)&ts[d][tq + i * 8];
  }
}

// ===========================================================================
// Fused kernel (r15 structure + queue-age discipline): 512 threads (8 waves),
// 128 q-rows/block, grid 8x64. Full per-hb K staged to LDS once (143 KB).
// Wave-independent after staging.
//  Phase 1: QK^T (LDS) + prev (depth-4 reg prefetch -> consume at age 4
//           chunk-bodies >= HBM latency) -> Z only.
//  Phase 2: recompute QK^T+exp (prev re-read L3-hot, depth-4), normalize
//           f32, stream att; PV via El A-frags + V reg-pipeline DEPTH 2:
//           V(c+2) issued at the END of chunk c (younger than P(c+3), so
//           V-consume never force-drains young prev; P-consume never drains
//           V). V consumed at age ~2 bodies >= L2/L3 latency.
// ===========================================================================
__global__ __launch_bounds__(512) void attn_all(
    const float* __restrict__ q, const float* __restrict__ kk,
    const _Float16* __restrict__ Vh, const float* __restrict__ prev,
    float* __restrict__ out, float* __restrict__ att) {
  __shared__ __align__(16) _Float16 Ks[1024][70];   // 143,360 B full-T K
  __shared__ __align__(16) _Float16 El[8][16][72];  // 18,432 B wave-private

  const int ltile = blockIdx.x;   // 0..7
  const int hb    = blockIdx.y;   // 0..63
  const int tid = threadIdx.x;
  const int w = tid >> 6, l = tid & 63, l15 = l & 15, lg = l >> 4;
  const int qrow = ltile * 128 + w * 16 + l15;

  // ---- stage ALL of K (f32 -> f16): 8 reps x (512 thr x 16 floats)
  {
    const int srow = tid >> 2, scol = (tid & 3) * 16;
    const float* kp0 = kk + (size_t)hb * T_ * D_;
#pragma unroll
    for (int rep = 0; rep < 8; ++rep) {
      const int r = rep * 128 + srow;
      const float* p = kp0 + (size_t)r * D_ + scol;
      f32x4 a = *(const f32x4*)(p);
      f32x4 b = *(const f32x4*)(p + 4);
      f32x4 cc = *(const f32x4*)(p + 8);
      f32x4 d = *(const f32x4*)(p + 12);
      half8 h0, h1;
#pragma unroll
      for (int e = 0; e < 4; ++e) {
        h0[e] = (_Float16)a[e];  h0[4 + e] = (_Float16)b[e];
        h1[e] = (_Float16)cc[e]; h1[4 + e] = (_Float16)d[e];
      }
      *(half8*)&Ks[r][scol] = h0;
      *(half8*)&Ks[r][scol + 8] = h1;
    }
  }

  // Q B-frag (swapped QK^T): lane holds Q[qrow][f*32 + lg*8 + e]
  half8 qb2[2];
  {
    const float* qp = q + ((size_t)hb * L_ + qrow) * D_ + lg * 8;
#pragma unroll
    for (int f = 0; f < 2; ++f)
#pragma unroll
      for (int e = 0; e < 8; ++e) qb2[f][e] = (_Float16)qp[f * 32 + e];
  }

  const float* prow = prev + ((size_t)hb * L_ + qrow) * (size_t)T_;

  // prev prefetch: depth 4 (consume age = 4 chunk bodies)
  f32x4 pb[4][4];
  auto pload = [&](int c, int s) {
#pragma unroll
    for (int nt = 0; nt < 4; ++nt)
      pb[s][nt] = *(const f32x4*)(prow + c * 64 + nt * 16 + lg * 4);
  };

  __syncthreads();   // K staged; no further block barriers

  // ======================= Phase 1: Z only ================================
  pload(0, 0); pload(1, 1); pload(2, 2); pload(3, 3);
  float zsum = 0.f;

#pragma unroll 4
  for (int c = 0; c < 16; ++c) {
    f32x4 pvv[4];
#pragma unroll
    for (int nt = 0; nt < 4; ++nt) pvv[nt] = pb[c & 3][nt];
    if (c < 12) pload(c + 4, c & 3);

#pragma unroll
    for (int nt = 0; nt < 4; ++nt) {
      const int trow = c * 64 + nt * 16 + l15;
      half8 ka0 = *(const half8*)&Ks[trow][lg * 8];
      half8 ka1 = *(const half8*)&Ks[trow][32 + lg * 8];
      f32x4 acc = {0.f, 0.f, 0.f, 0.f};
      acc = __builtin_amdgcn_mfma_f32_16x16x32_f16(ka0, qb2[0], acc, 0, 0, 0);
      acc = __builtin_amdgcn_mfma_f32_16x16x32_f16(ka1, qb2[1], acc, 0, 0, 0);
      zsum += __expf(acc[0] * SCALE + pvv[nt][0]);
      zsum += __expf(acc[1] * SCALE + pvv[nt][1]);
      zsum += __expf(acc[2] * SCALE + pvv[nt][2]);
      zsum += __expf(acc[3] * SCALE + pvv[nt][3]);
    }
  }

  zsum += __shfl_xor(zsum, 16, 64);
  zsum += __shfl_xor(zsum, 32, 64);
  const float rzq = 1.0f / zsum;

  // ======================= Phase 2: att + PV ==============================
  const _Float16* vbh = Vh + (size_t)hb * D_ * T_;  // [d][t] f16
  float* arow = att + ((size_t)hb * L_ + qrow) * (size_t)T_;

  // V register pipeline, depth 2: vr[parity][ks*4+nd]
  half8 vr[2][8];
  auto vload = [&](int c, int s) {
#pragma unroll
    for (int ks = 0; ks < 2; ++ks)
#pragma unroll
      for (int nd = 0; nd < 4; ++nd)
        vr[s][ks * 4 + nd] =
            *(const half8*)(vbh + (size_t)(nd * 16 + l15) * T_ + c * 64 +
                            ks * 32 + lg * 8);
  };

  pload(0, 0); pload(1, 1); pload(2, 2); pload(3, 3);   // L3-hot re-read
  vload(0, 0);
  vload(1, 1);

  f32x4 oacc[4];
#pragma unroll
  for (int nd = 0; nd < 4; ++nd) oacc[nd] = (f32x4){0.f, 0.f, 0.f, 0.f};

#pragma unroll 4
  for (int c = 0; c < 16; ++c) {
    // consume prev at age 4 (never drains the younger V pipeline)
    f32x4 pvv[4];
#pragma unroll
    for (int nt = 0; nt < 4; ++nt) pvv[nt] = pb[c & 3][nt];
    if (c < 12) pload(c + 4, c & 3);

    // recompute scores, normalize, stream att, build El
#pragma unroll
    for (int nt = 0; nt < 4; ++nt) {
      const int trow = c * 64 + nt * 16 + l15;
      half8 ka0 = *(const half8*)&Ks[trow][lg * 8];
      half8 ka1 = *(const half8*)&Ks[trow][32 + lg * 8];
      f32x4 acc = {0.f, 0.f, 0.f, 0.f};
      acc = __builtin_amdgcn_mfma_f32_16x16x32_f16(ka0, qb2[0], acc, 0, 0, 0);
      acc = __builtin_amdgcn_mfma_f32_16x16x32_f16(ka1, qb2[1], acc, 0, 0, 0);

      f32x4 s;
      s[0] = __expf(acc[0] * SCALE + pvv[nt][0]) * rzq;
      s[1] = __expf(acc[1] * SCALE + pvv[nt][1]) * rzq;
      s[2] = __expf(acc[2] * SCALE + pvv[nt][2]) * rzq;
      s[3] = __expf(acc[3] * SCALE + pvv[nt][3]) * rzq;
      *(f32x4*)(arow + c * 64 + nt * 16 + lg * 4) = s;

      half4 ev;
      ev[0] = (_Float16)s[0]; ev[1] = (_Float16)s[1];
      ev[2] = (_Float16)s[2]; ev[3] = (_Float16)s[3];
      *(half4*)&El[w][l15][nt * 16 + lg * 4] = ev;
    }

    // PV: A-frag from El (same-wave DS in-order), B-frag = vr at age ~2
#pragma unroll
    for (int ks = 0; ks < 2; ++ks) {
      half8 af = *(const half8*)&El[w][l15][ks * 32 + lg * 8];
#pragma unroll
      for (int nd = 0; nd < 4; ++nd)
        oacc[nd] = __builtin_amdgcn_mfma_f32_16x16x32_f16(
            af, vr[c & 1][ks * 4 + nd], oacc[nd], 0, 0, 0);
    }

    // issue V(c+2) LAST (younger than P(c+3): consuming it later never
    // force-drains prev; buffer c&1 was fully consumed just above)
    if (c < 14) vload(c + 2, c & 1);
  }

  // epilogue: oacc[nd][i] = O[q = w*16 + lg*4 + i][d = nd*16 + l15]
  float* outw =
      out + ((size_t)hb * L_ + ltile * 128 + w * 16 + lg * 4) * (size_t)D_;
#pragma unroll
  for (int nd = 0; nd < 4; ++nd)
#pragma unroll
    for (int i = 0; i < 4; ++i)
      outw[(size_t)i * D_ + nd * 16 + l15] = oacc[nd][i];
}

extern "C" void kernel_launch(void* const* d_in, const int* in_sizes, int n_in,
                              void* d_out, int out_size, void* d_ws,
                              size_t ws_size, hipStream_t stream) {
  const float* q    = (const float*)d_in[0];  // (H,B,L,D)
  const float* k    = (const float*)d_in[1];  // (H,B,T,D)
  const float* v    = (const float*)d_in[2];  // (H,B,T,D)
  const float* prev = (const float*)d_in[3];  // (H,B,L,T)

  float* out = (float*)d_out;                 // (H,B,L,D)
  float* att = out + (size_t)HB_ * L_ * D_;   // (H,B,L,T)

  _Float16* Vh = (_Float16*)d_ws;             // 8 MB (ws >= 16 MB proven)

  cvt_v<<<dim3(T_ / 128, HB_), 256, 0, stream>>>(v, Vh);
  attn_all<<<dim3(L_ / 128, HB_), 512, 0, stream>>>(q, k, Vh, prev, out, att);
}

// Round 18
// 209.381 us; speedup vs baseline: 1.5464x; 1.0839x over previous
//
#include <hip/hip_runtime.h>

#define SCALE 0.125f

constexpr int L_ = 1024, T_ = 1024, D_ = 64, HB_ = 64;

using f32x4 = __attribute__((ext_vector_type(4))) float;
using half8 = __attribute__((ext_vector_type(8))) _Float16;
using half4 = __attribute__((ext_vector_type(4))) _Float16;

// ===========================================================================
// Prologue: V f32 [hb][t][d] -> Vh f16 transposed [hb][d][t]. (r10-proven)
// ===========================================================================
__global__ __launch_bounds__(256) void cvt_v(const float* __restrict__ v,
                                             _Float16* __restrict__ vh) {
  __shared__ _Float16 ts[64][136];
  const int tid = threadIdx.x;
  const int hb = blockIdx.y;
  const int t0 = blockIdx.x * 128;
  {
    const int tr = tid >> 1, dh = (tid & 1) * 32;
    const float* p = v + ((size_t)hb * T_ + t0 + tr) * D_ + dh;
#pragma unroll
    for (int i = 0; i < 8; ++i) {
      f32x4 r = *(const f32x4*)(p + i * 4);
#pragma unroll
      for (int e = 0; e < 4; ++e) ts[dh + i * 4 + e][tr] = (_Float16)r[e];
    }
  }
  __syncthreads();
  {
    const int d = tid >> 2, tq = (tid & 3) * 32;
    _Float16* qo = vh + ((size_t)hb * D_ + d) * T_ + t0 + tq;
#pragma unroll
    for (int i = 0; i < 4; ++i)
      *(half8*)(qo + i * 8) = *(const half8*)&ts[d][tq + i * 8];
  }
}

// ===========================================================================
// Fused kernel (r17 + coalesced-stream remap): 512 threads (8 waves),
// 128 q-rows/block, grid 8x64. Full per-hb K in LDS (143 KB). Per-wave f16
// remap tile Pl[16][64] (XOR-swizzled, 2 KB) turns prev loads and att stores
// into 4-rows x 256B-dense per-instruction patterns:
//   pload: lane l -> row (l>>4)+4i, cols (l&15)*4  (4x 256B aligned segments)
//   pstage: regs -> f16 tile (same-wave DS, no barriers)
//   frags:  read tile at MFMA lane mapping (row l15)
//   writeback: s -> same tile slots; store-out: 4 instrs of 4 rows x 256B
//   PV A-frag: b128 read from tile (El array deleted)
// ===========================================================================
__global__ __launch_bounds__(512) void attn_all(
    const float* __restrict__ q, const float* __restrict__ kk,
    const _Float16* __restrict__ Vh, const float* __restrict__ prev,
    float* __restrict__ out, float* __restrict__ att) {
  __shared__ __align__(16) _Float16 Ks[1024][70];   // 143,360 B full-T K
  __shared__ __align__(16) _Float16 Pl[8][16][64];  // 16,384 B remap tiles

  const int ltile = blockIdx.x;   // 0..7
  const int hb    = blockIdx.y;   // 0..63
  const int tid = threadIdx.x;
  const int w = tid >> 6, l = tid & 63, l15 = l & 15, lg = l >> 4;
  const int qrow = ltile * 128 + w * 16 + l15;

  // XOR-swizzled byte accessor for this wave's tile (16B granule swizzle,
  // row stride 128 B; preserves 8B/16B alignment)
  auto plb = [&](int row, int byte) -> _Float16* {
    return (_Float16*)((unsigned char*)&Pl[w][0][0] + row * 128 +
                       ((unsigned)byte ^ (((unsigned)row & 7) << 4)));
  };

  // ---- stage ALL of K (f32 -> f16): 8 reps x (512 thr x 16 floats)
  {
    const int srow = tid >> 2, scol = (tid & 3) * 16;
    const float* kp0 = kk + (size_t)hb * T_ * D_;
#pragma unroll
    for (int rep = 0; rep < 8; ++rep) {
      const int r = rep * 128 + srow;
      const float* p = kp0 + (size_t)r * D_ + scol;
      f32x4 a = *(const f32x4*)(p);
      f32x4 b = *(const f32x4*)(p + 4);
      f32x4 cc = *(const f32x4*)(p + 8);
      f32x4 d = *(const f32x4*)(p + 12);
      half8 h0, h1;
#pragma unroll
      for (int e = 0; e < 4; ++e) {
        h0[e] = (_Float16)a[e];  h0[4 + e] = (_Float16)b[e];
        h1[e] = (_Float16)cc[e]; h1[4 + e] = (_Float16)d[e];
      }
      *(half8*)&Ks[r][scol] = h0;
      *(half8*)&Ks[r][scol + 8] = h1;
    }
  }

  // Q B-frag (swapped QK^T): lane holds Q[qrow][f*32 + lg*8 + e]
  half8 qb2[2];
  {
    const float* qp = q + ((size_t)hb * L_ + qrow) * D_ + lg * 8;
#pragma unroll
    for (int f = 0; f < 2; ++f)
#pragma unroll
      for (int e = 0; e < 8; ++e) qb2[f][e] = (_Float16)qp[f * 32 + e];
  }

  // coalesced prev pattern: lane -> row (l>>4)+4i, cols (l&15)*4
  const float* prowb =
      prev + ((size_t)hb * L_ + ltile * 128 + w * 16) * (size_t)T_;
  const int cr = l >> 4, cc4 = (l & 15) * 4;

  f32x4 pr[2][4];
  auto pload = [&](int c, int s) {
#pragma unroll
    for (int i = 0; i < 4; ++i)
      pr[s][i] =
          *(const f32x4*)(prowb + (size_t)(cr + 4 * i) * T_ + c * 64 + cc4);
  };
  auto pstage = [&](int s) {   // regs -> f16 tile (consume point of pr[s])
#pragma unroll
    for (int i = 0; i < 4; ++i) {
      half4 h;
      h[0] = (_Float16)pr[s][i][0]; h[1] = (_Float16)pr[s][i][1];
      h[2] = (_Float16)pr[s][i][2]; h[3] = (_Float16)pr[s][i][3];
      *(half4*)plb(cr + 4 * i, cc4 * 2) = h;
    }
  };

  __syncthreads();   // K staged; no further block barriers

  // ======================= Phase 1: Z only ================================
  pload(0, 0);
  pload(1, 1);
  float zsum = 0.f;

#pragma unroll 2
  for (int c = 0; c < 16; ++c) {
    pstage(c & 1);
    if (c < 14) pload(c + 2, c & 1);

#pragma unroll
    for (int nt = 0; nt < 4; ++nt) {
      const int trow = c * 64 + nt * 16 + l15;
      half8 ka0 = *(const half8*)&Ks[trow][lg * 8];
      half8 ka1 = *(const half8*)&Ks[trow][32 + lg * 8];
      f32x4 acc = {0.f, 0.f, 0.f, 0.f};
      acc = __builtin_amdgcn_mfma_f32_16x16x32_f16(ka0, qb2[0], acc, 0, 0, 0);
      acc = __builtin_amdgcn_mfma_f32_16x16x32_f16(ka1, qb2[1], acc, 0, 0, 0);

      half4 hv = *(const half4*)plb(l15, (nt * 16 + lg * 4) * 2);
      zsum += __expf(acc[0] * SCALE + (float)hv[0]);
      zsum += __expf(acc[1] * SCALE + (float)hv[1]);
      zsum += __expf(acc[2] * SCALE + (float)hv[2]);
      zsum += __expf(acc[3] * SCALE + (float)hv[3]);
    }
  }

  zsum += __shfl_xor(zsum, 16, 64);
  zsum += __shfl_xor(zsum, 32, 64);
  const float rzq = 1.0f / zsum;

  // ======================= Phase 2: att + PV ==============================
  const _Float16* vbh = Vh + (size_t)hb * D_ * T_;  // [d][t] f16
  float* attb = att + ((size_t)hb * L_ + ltile * 128 + w * 16) * (size_t)T_;

  half8 vr[2][8];
  auto vload = [&](int c, int s) {
#pragma unroll
    for (int ks = 0; ks < 2; ++ks)
#pragma unroll
      for (int nd = 0; nd < 4; ++nd)
        vr[s][ks * 4 + nd] =
            *(const half8*)(vbh + (size_t)(nd * 16 + l15) * T_ + c * 64 +
                            ks * 32 + lg * 8);
  };

  pload(0, 0);   // L3-hot re-read
  pload(1, 1);
  vload(0, 0);
  vload(1, 1);

  f32x4 oacc[4];
#pragma unroll
  for (int nd = 0; nd < 4; ++nd) oacc[nd] = (f32x4){0.f, 0.f, 0.f, 0.f};

#pragma unroll 2
  for (int c = 0; c < 16; ++c) {
    pstage(c & 1);
    if (c < 14) pload(c + 2, c & 1);

    // recompute scores, normalize, write s back into the tile (same slots)
#pragma unroll
    for (int nt = 0; nt < 4; ++nt) {
      const int trow = c * 64 + nt * 16 + l15;
      half8 ka0 = *(const half8*)&Ks[trow][lg * 8];
      half8 ka1 = *(const half8*)&Ks[trow][32 + lg * 8];
      f32x4 acc = {0.f, 0.f, 0.f, 0.f};
      acc = __builtin_amdgcn_mfma_f32_16x16x32_f16(ka0, qb2[0], acc, 0, 0, 0);
      acc = __builtin_amdgcn_mfma_f32_16x16x32_f16(ka1, qb2[1], acc, 0, 0, 0);

      half4 hv = *(const half4*)plb(l15, (nt * 16 + lg * 4) * 2);
      float s0 = __expf(acc[0] * SCALE + (float)hv[0]) * rzq;
      float s1 = __expf(acc[1] * SCALE + (float)hv[1]) * rzq;
      float s2 = __expf(acc[2] * SCALE + (float)hv[2]) * rzq;
      float s3 = __expf(acc[3] * SCALE + (float)hv[3]) * rzq;
      half4 sv;
      sv[0] = (_Float16)s0; sv[1] = (_Float16)s1;
      sv[2] = (_Float16)s2; sv[3] = (_Float16)s3;
      *(half4*)plb(l15, (nt * 16 + lg * 4) * 2) = sv;
    }

    // PV: A-frag b128 straight from the tile (f16 s values), B = vr
#pragma unroll
    for (int ks = 0; ks < 2; ++ks) {
      half8 af = *(const half8*)plb(l15, (ks * 32 + lg * 8) * 2);
#pragma unroll
      for (int nd = 0; nd < 4; ++nd)
        oacc[nd] = __builtin_amdgcn_mfma_f32_16x16x32_f16(
            af, vr[c & 1][ks * 4 + nd], oacc[nd], 0, 0, 0);
    }

    // att store-out: 4 instrs, each 4 rows x 256B dense full lines
#pragma unroll
    for (int i = 0; i < 4; ++i) {
      half4 hv = *(const half4*)plb(cr + 4 * i, cc4 * 2);
      f32x4 sv = {(float)hv[0], (float)hv[1], (float)hv[2], (float)hv[3]};
      *(f32x4*)(attb + (size_t)(cr + 4 * i) * T_ + c * 64 + cc4) = sv;
    }

    if (c < 14) vload(c + 2, c & 1);   // issue V last (youngest in queue)
  }

  // epilogue: oacc[nd][i] = O[q = w*16 + lg*4 + i][d = nd*16 + l15]
  float* outw =
      out + ((size_t)hb * L_ + ltile * 128 + w * 16 + lg * 4) * (size_t)D_;
#pragma unroll
  for (int nd = 0; nd < 4; ++nd)
#pragma unroll
    for (int i = 0; i < 4; ++i)
      outw[(size_t)i * D_ + nd * 16 + l15] = oacc[nd][i];
}

extern "C" void kernel_launch(void* const* d_in, const int* in_sizes, int n_in,
                              void* d_out, int out_size, void* d_ws,
                              size_t ws_size, hipStream_t stream) {
  const float* q    = (const float*)d_in[0];  // (H,B,L,D)
  const float* k    = (const float*)d_in[1];  // (H,B,T,D)
  const float* v    = (const float*)d_in[2];  // (H,B,T,D)
  const float* prev = (const float*)d_in[3];  // (H,B,L,T)

  float* out = (float*)d_out;                 // (H,B,L,D)
  float* att = out + (size_t)HB_ * L_ * D_;   // (H,B,L,T)

  _Float16* Vh = (_Float16*)d_ws;             // 8 MB (ws >= 16 MB proven)

  cvt_v<<<dim3(T_ / 128, HB_), 256, 0, stream>>>(v, Vh);
  attn_all<<<dim3(L_ / 128, HB_), 512, 0, stream>>>(q, k, Vh, prev, out, att);
}